// Round 3
// baseline (149.268 us; speedup 1.0000x reference)
//
#include <hip/hip_runtime.h>
#include <cstdint>
#include <cstddef>

// Problem constants (from reference setup_inputs / module constants)
#define RB  2
#define RC  256
#define RH  100
#define RW  152
#define RHW (RH * RW)      // 15200
#define HWQ (RHW / 4)      // 3800 float4 per channel row
#define RPH 7
#define RPW 7
#define RNB (RPH * RPW)    // 49 bins per ROI
#define HTILES ((HWQ + 31) / 32)   // 119 hw-quad tiles of 32 (128 elems)
constexpr float kScale = 0.0625f;

// ---------------------------------------------------------------------------
// Kernel 1: NCHW -> NHWC transpose, float4 on BOTH global sides.
// Tile = 32 channels x 128 hw. Element transpose via 17 KB LDS.
// Phase1: each thread float4-loads 4 hw elems of one channel, scatters 4
//   scalars into lds[hw][c] (bank ~4-way, cheap). Phase2: thread gathers 4
//   consecutive channels of one hw (reads ~2-way), float4-stores to NHWC.
// ---------------------------------------------------------------------------
__global__ __launch_bounds__(256) void transpose_nchw_nhwc(
    const float* __restrict__ in, float* __restrict__ out) {
  __shared__ float lds[128 * 33];   // [hw 0..127][c 0..31], +1 pad
  int bid = blockIdx.x;             // 0 .. RB*8*HTILES-1
  const int b  = bid / (8 * HTILES);
  bid -= b * (8 * HTILES);
  const int c0 = (bid / HTILES) * 32;
  const int ht = bid - (bid / HTILES) * HTILES;
  const int t  = threadIdx.x;

  const float4* in4  = (const float4*)(in + (size_t)b * RC * RHW);
  float*        outb = out + (size_t)b * RHW * RC;

  {  // phase 1: read [c][hw] float4, scatter to lds[hw][c]
    const int tx = t & 31;          // hw-quad within tile
    const int ty = t >> 5;          // channel 0..7 (x4 iters)
    const int qt = ht * 32 + tx;    // global hw-quad
    if (qt < HWQ) {
#pragma unroll
      for (int j = 0; j < 4; ++j) {
        const int cl = ty + 8 * j;
        const float4 v = in4[(size_t)(c0 + cl) * HWQ + qt];
        const int hwl = tx * 4;
        lds[(hwl + 0) * 33 + cl] = v.x;
        lds[(hwl + 1) * 33 + cl] = v.y;
        lds[(hwl + 2) * 33 + cl] = v.z;
        lds[(hwl + 3) * 33 + cl] = v.w;
      }
    }
  }
  __syncthreads();
  {  // phase 2: gather c-quads, float4-store to [hw][c]
    const int cq = t & 7;           // channel quad: c = c0 + 4cq..4cq+3
    const int hr = t >> 3;          // hw row 0..31 (x4 iters)
#pragma unroll
    for (int j = 0; j < 4; ++j) {
      const int hwl = hr + 32 * j;
      const int hw  = ht * 128 + hwl;
      if (hw < RHW) {
        float4 o;
        o.x = lds[hwl * 33 + 4 * cq + 0];
        o.y = lds[hwl * 33 + 4 * cq + 1];
        o.z = lds[hwl * 33 + 4 * cq + 2];
        o.w = lds[hwl * 33 + 4 * cq + 3];
        ((float4*)outb)[(size_t)hw * 64 + (c0 >> 2) + cq] = o;
      }
    }
  }
}

// ---------------------------------------------------------------------------
// Kernel 2: RoIAlign on NHWC features. TWO blocks per ROI (128 channels
// each) -> 25 KB LDS -> 6 blocks/CU, 2048 blocks for latency hiding.
// Lane cg owns channels 2cg..2cg+1 of its half (float2 corner loads:
// 64 lanes x 8 B = the half's full 512 B channel vector, coalesced).
// Wave (t>>6) strides over the 49 bins -> wave-uniform coord math.
// Results staged in LDS in output order -> float2-coalesced epilogue.
// ---------------------------------------------------------------------------
__global__ __launch_bounds__(256, 6) void roi_align_nhwc(
    const float* __restrict__ feat,   // [B][H][W][C]
    const float* __restrict__ rois,   // [R][5]
    float* __restrict__ out) {        // [R][C][7][7]
  __shared__ float lds[128 * RNB];    // 25088 B, out-order [c_local][bi]

  const int r    = blockIdx.x >> 1;
  const int half = blockIdx.x & 1;
  const int t    = threadIdx.x;
  const int cg   = t & 63;   // owns local channels 2cg, 2cg+1
  const int wg   = t >> 6;   // wave id 0..3

  const float* roi = rois + (size_t)r * 5;
  int b = (int)roi[0];
  b = (b < 0) ? 0 : (b >= RB ? RB - 1 : b);
  const float sw    = roi[1] * kScale;
  const float sh    = roi[2] * kScale;
  const float ew    = roi[3] * kScale;
  const float eh    = roi[4] * kScale;
  const float roi_w = fmaxf(ew - sw, 1.0f);
  const float roi_h = fmaxf(eh - sh, 1.0f);
  const float bin_w = roi_w / 7.0f;
  const float bin_h = roi_h / 7.0f;

  const float2* fb  = (const float2*)(feat + (size_t)b * RHW * RC);
  const int     off = half * 64 + cg;   // float2 index within a position

  for (int bi = wg; bi < RNB; bi += 4) {
    const int ph = bi / RPW;
    const int pw = bi - ph * RPW;

    float ax = 0.f, ay = 0.f;
#pragma unroll
    for (int s = 0; s < 4; ++s) {
      const int iy = s >> 1;
      const int ix = s & 1;
      const float y = sh + ((float)ph + (iy ? 0.75f : 0.25f)) * bin_h;
      const float x = sw + ((float)pw + (ix ? 0.75f : 0.25f)) * bin_w;
      if (y < -1.0f || y > (float)RH || x < -1.0f || x > (float)RW) continue;

      const float yc = fminf(fmaxf(y, 0.0f), (float)(RH - 1));
      const float xc = fminf(fmaxf(x, 0.0f), (float)(RW - 1));
      const int y0 = (int)yc;
      const int x0 = (int)xc;
      const int y1 = (y0 + 1 < RH) ? y0 + 1 : RH - 1;
      const int x1 = (x0 + 1 < RW) ? x0 + 1 : RW - 1;
      const float ly = yc - (float)y0;
      const float lx = xc - (float)x0;
      const float hy = 1.0f - ly;
      const float hx = 1.0f - lx;
      const float w11 = hy * hx, w12 = hy * lx, w21 = ly * hx, w22 = ly * lx;

      const float2 v11 = fb[(size_t)(y0 * RW + x0) * 128 + off];
      const float2 v12 = fb[(size_t)(y0 * RW + x1) * 128 + off];
      const float2 v21 = fb[(size_t)(y1 * RW + x0) * 128 + off];
      const float2 v22 = fb[(size_t)(y1 * RW + x1) * 128 + off];

      ax += w11 * v11.x + w12 * v12.x + w21 * v21.x + w22 * v22.x;
      ay += w11 * v11.y + w12 * v12.y + w21 * v21.y + w22 * v22.y;
    }

    const int cbase = (cg * 2) * RNB + bi;
    lds[cbase + 0 * RNB] = ax * 0.25f;
    lds[cbase + 1 * RNB] = ay * 0.25f;
  }

  __syncthreads();

  // Epilogue: 6272 floats = 3136 float2 = 12*256 + 64, coalesced.
  float2* outr = (float2*)(out + (size_t)r * (RC * RNB) + half * (128 * RNB));
  const float2* lds2 = (const float2*)lds;
#pragma unroll
  for (int it = 0; it < 12; ++it)
    outr[it * 256 + t] = lds2[it * 256 + t];
  if (t < 64)
    outr[12 * 256 + t] = lds2[12 * 256 + t];
}

// ---------------------------------------------------------------------------
// Fallback: direct NCHW gather (workspace too small or misaligned pointers).
// ---------------------------------------------------------------------------
__global__ __launch_bounds__(256) void roi_align_nchw(
    const float* __restrict__ feat,   // [B][C][H][W]
    const float* __restrict__ rois,
    float* __restrict__ out) {
  const int r = blockIdx.x;
  const int c = threadIdx.x;

  const float* roi = rois + (size_t)r * 5;
  int b = (int)roi[0];
  b = (b < 0) ? 0 : (b >= RB ? RB - 1 : b);
  const float sw    = roi[1] * kScale;
  const float sh    = roi[2] * kScale;
  const float ew    = roi[3] * kScale;
  const float eh    = roi[4] * kScale;
  const float roi_w = fmaxf(ew - sw, 1.0f);
  const float roi_h = fmaxf(eh - sh, 1.0f);
  const float bin_w = roi_w / 7.0f;
  const float bin_h = roi_h / 7.0f;

  const float* fb = feat + ((size_t)b * RC + c) * RHW;

  for (int bi = 0; bi < RNB; ++bi) {
    const int ph = bi / RPW;
    const int pw = bi - ph * RPW;
    float acc = 0.f;
#pragma unroll
    for (int s = 0; s < 4; ++s) {
      const int iy = s >> 1;
      const int ix = s & 1;
      const float y = sh + ((float)ph + (iy ? 0.75f : 0.25f)) * bin_h;
      const float x = sw + ((float)pw + (ix ? 0.75f : 0.25f)) * bin_w;
      if (y < -1.0f || y > (float)RH || x < -1.0f || x > (float)RW) continue;

      const float yc = fminf(fmaxf(y, 0.0f), (float)(RH - 1));
      const float xc = fminf(fmaxf(x, 0.0f), (float)(RW - 1));
      const int y0 = (int)yc;
      const int x0 = (int)xc;
      const int y1 = (y0 + 1 < RH) ? y0 + 1 : RH - 1;
      const int x1 = (x0 + 1 < RW) ? x0 + 1 : RW - 1;
      const float ly = yc - (float)y0;
      const float lx = xc - (float)x0;
      const float hy = 1.0f - ly;
      const float hx = 1.0f - lx;

      acc += (hy * hx) * fb[y0 * RW + x0] + (hy * lx) * fb[y0 * RW + x1] +
             (ly * hx) * fb[y1 * RW + x0] + (ly * lx) * fb[y1 * RW + x1];
    }
    out[((size_t)r * RC + c) * RNB + bi] = acc * 0.25f;
  }
}

// ---------------------------------------------------------------------------
extern "C" void kernel_launch(void* const* d_in, const int* in_sizes, int n_in,
                              void* d_out, int out_size, void* d_ws, size_t ws_size,
                              hipStream_t stream) {
  const float* feat = (const float*)d_in[0];
  const float* rois = (const float*)d_in[1];
  float* out = (float*)d_out;
  const int R = in_sizes[1] / 5;

  const size_t need = (size_t)RB * RC * RHW * sizeof(float);  // 31.1 MB
  const bool aligned16 =
      (((uintptr_t)d_ws | (uintptr_t)d_in[0] | (uintptr_t)d_out) & 15) == 0;

  if (ws_size >= need && aligned16 && d_ws != nullptr) {
    float* nhwc = (float*)d_ws;
    transpose_nchw_nhwc<<<RB * 8 * HTILES, 256, 0, stream>>>(feat, nhwc);
    roi_align_nhwc<<<R * 2, 256, 0, stream>>>(nhwc, rois, out);
  } else {
    roi_align_nchw<<<R, 256, 0, stream>>>(feat, rois, out);
  }
}

// Round 4
// 143.205 us; speedup vs baseline: 1.0423x; 1.0423x over previous
//
#include <hip/hip_runtime.h>
#include <cstdint>
#include <cstddef>

// Problem constants (from reference setup_inputs / module constants)
#define RB  2
#define RC  256
#define RH  100
#define RW  152
#define RHW (RH * RW)      // 15200
#define HWQ (RHW / 4)      // 3800 float4 per channel row
#define RPH 7
#define RPW 7
#define RNB (RPH * RPW)    // 49 bins per ROI
#define HTILES ((HWQ + 31) / 32)   // 119 hw-quad tiles of 32 (128 elems)
constexpr float kScale = 0.0625f;

// ---------------------------------------------------------------------------
// Kernel 1: NCHW -> NHWC transpose, float4 on BOTH global sides.
// (unchanged from round 3 — not the current bottleneck)
// ---------------------------------------------------------------------------
__global__ __launch_bounds__(256) void transpose_nchw_nhwc(
    const float* __restrict__ in, float* __restrict__ out) {
  __shared__ float lds[128 * 33];   // [hw 0..127][c 0..31], +1 pad
  int bid = blockIdx.x;             // 0 .. RB*8*HTILES-1
  const int b  = bid / (8 * HTILES);
  bid -= b * (8 * HTILES);
  const int c0 = (bid / HTILES) * 32;
  const int ht = bid - (bid / HTILES) * HTILES;
  const int t  = threadIdx.x;

  const float4* in4  = (const float4*)(in + (size_t)b * RC * RHW);
  float*        outb = out + (size_t)b * RHW * RC;

  {  // phase 1: read [c][hw] float4, scatter to lds[hw][c]
    const int tx = t & 31;          // hw-quad within tile
    const int ty = t >> 5;          // channel 0..7 (x4 iters)
    const int qt = ht * 32 + tx;    // global hw-quad
    if (qt < HWQ) {
#pragma unroll
      for (int j = 0; j < 4; ++j) {
        const int cl = ty + 8 * j;
        const float4 v = in4[(size_t)(c0 + cl) * HWQ + qt];
        const int hwl = tx * 4;
        lds[(hwl + 0) * 33 + cl] = v.x;
        lds[(hwl + 1) * 33 + cl] = v.y;
        lds[(hwl + 2) * 33 + cl] = v.z;
        lds[(hwl + 3) * 33 + cl] = v.w;
      }
    }
  }
  __syncthreads();
  {  // phase 2: gather c-quads, float4-store to [hw][c]
    const int cq = t & 7;           // channel quad: c = c0 + 4cq..4cq+3
    const int hr = t >> 3;          // hw row 0..31 (x4 iters)
#pragma unroll
    for (int j = 0; j < 4; ++j) {
      const int hwl = hr + 32 * j;
      const int hw  = ht * 128 + hwl;
      if (hw < RHW) {
        float4 o;
        o.x = lds[hwl * 33 + 4 * cq + 0];
        o.y = lds[hwl * 33 + 4 * cq + 1];
        o.z = lds[hwl * 33 + 4 * cq + 2];
        o.w = lds[hwl * 33 + 4 * cq + 3];
        ((float4*)outb)[(size_t)hw * 64 + (c0 >> 2) + cq] = o;
      }
    }
  }
}

// ---------------------------------------------------------------------------
// Kernel 2: RoIAlign on NHWC features. TWO blocks per ROI (128 ch each),
// 25 KB LDS -> 6 blocks/CU. BRANCHLESS inner loop: validity folded into the
// y-weights as a 0/1 multiplier; clamped indices make unconditional loads
// safe. Per bin only 2 distinct y's and 2 x's -> compute each once, combine.
// All 16 corner loads per bin issue back-to-back (MLP 16, x2 with unroll).
// ---------------------------------------------------------------------------
__global__ __launch_bounds__(256, 6) void roi_align_nhwc(
    const float* __restrict__ feat,   // [B][H][W][C]
    const float* __restrict__ rois,   // [R][5]
    float* __restrict__ out) {        // [R][C][7][7]
  __shared__ float lds[128 * RNB];    // 25088 B, out-order [c_local][bi]

  const int r    = blockIdx.x >> 1;
  const int half = blockIdx.x & 1;
  const int t    = threadIdx.x;
  const int cg   = t & 63;   // owns local channels 2cg, 2cg+1
  const int wg   = t >> 6;   // wave id 0..3

  const float* roi = rois + (size_t)r * 5;
  int b = (int)roi[0];
  b = (b < 0) ? 0 : (b >= RB ? RB - 1 : b);
  const float sw    = roi[1] * kScale;
  const float sh    = roi[2] * kScale;
  const float ew    = roi[3] * kScale;
  const float eh    = roi[4] * kScale;
  const float roi_w = fmaxf(ew - sw, 1.0f);
  const float roi_h = fmaxf(eh - sh, 1.0f);
  const float bin_w = roi_w / 7.0f;
  const float bin_h = roi_h / 7.0f;

  const float2* fb  = (const float2*)(feat + (size_t)b * RHW * RC);
  const int     off = half * 64 + cg;   // float2 index within a position

#pragma unroll 2
  for (int bi = wg; bi < RNB; bi += 4) {
    const int ph = bi / RPW;
    const int pw = bi - ph * RPW;

    // ---- y pair (iy = 0,1): weights (scaled by validity) + row offsets ----
    float hyv[2], lyv[2];
    int   ry0[2], ry1[2];
#pragma unroll
    for (int iy = 0; iy < 2; ++iy) {
      const float y  = sh + ((float)ph + (iy ? 0.75f : 0.25f)) * bin_h;
      const float vm = (y >= -1.0f && y <= (float)RH) ? 1.0f : 0.0f;
      const float yc = fminf(fmaxf(y, 0.0f), (float)(RH - 1));
      const int y0 = (int)yc;
      const int y1 = (y0 + 1 < RH) ? y0 + 1 : RH - 1;
      const float ly = yc - (float)y0;
      hyv[iy] = (1.0f - ly) * vm;
      lyv[iy] = ly * vm;
      ry0[iy] = y0 * (RW * 128);
      ry1[iy] = y1 * (RW * 128);
    }
    // ---- x pair (ix = 0,1): weights (scaled by validity) + col offsets ----
    float hxv[2], lxv[2];
    int   cx0[2], cx1[2];
#pragma unroll
    for (int ix = 0; ix < 2; ++ix) {
      const float x  = sw + ((float)pw + (ix ? 0.75f : 0.25f)) * bin_w;
      const float vm = (x >= -1.0f && x <= (float)RW) ? 1.0f : 0.0f;
      const float xc = fminf(fmaxf(x, 0.0f), (float)(RW - 1));
      const int x0 = (int)xc;
      const int x1 = (x0 + 1 < RW) ? x0 + 1 : RW - 1;
      const float lx = xc - (float)x0;
      hxv[ix] = (1.0f - lx) * vm;
      lxv[ix] = lx * vm;
      cx0[ix] = x0 * 128 + off;
      cx1[ix] = x1 * 128 + off;
    }

    float ax = 0.f, ay = 0.f;
#pragma unroll
    for (int s = 0; s < 4; ++s) {
      const int iy = s >> 1;
      const int ix = s & 1;
      const float2 v11 = fb[ry0[iy] + cx0[ix]];
      const float2 v12 = fb[ry0[iy] + cx1[ix]];
      const float2 v21 = fb[ry1[iy] + cx0[ix]];
      const float2 v22 = fb[ry1[iy] + cx1[ix]];
      const float w11 = hyv[iy] * hxv[ix];
      const float w12 = hyv[iy] * lxv[ix];
      const float w21 = lyv[iy] * hxv[ix];
      const float w22 = lyv[iy] * lxv[ix];
      ax += w11 * v11.x + w12 * v12.x + w21 * v21.x + w22 * v22.x;
      ay += w11 * v11.y + w12 * v12.y + w21 * v21.y + w22 * v22.y;
    }

    const int cbase = (cg * 2) * RNB + bi;
    lds[cbase + 0 * RNB] = ax * 0.25f;
    lds[cbase + 1 * RNB] = ay * 0.25f;
  }

  __syncthreads();

  // Epilogue: 6272 floats = 3136 float2 = 12*256 + 64, coalesced.
  float2* outr = (float2*)(out + (size_t)r * (RC * RNB) + half * (128 * RNB));
  const float2* lds2 = (const float2*)lds;
#pragma unroll
  for (int it = 0; it < 12; ++it)
    outr[it * 256 + t] = lds2[it * 256 + t];
  if (t < 64)
    outr[12 * 256 + t] = lds2[12 * 256 + t];
}

// ---------------------------------------------------------------------------
// Fallback: direct NCHW gather (workspace too small or misaligned pointers).
// ---------------------------------------------------------------------------
__global__ __launch_bounds__(256) void roi_align_nchw(
    const float* __restrict__ feat,   // [B][C][H][W]
    const float* __restrict__ rois,
    float* __restrict__ out) {
  const int r = blockIdx.x;
  const int c = threadIdx.x;

  const float* roi = rois + (size_t)r * 5;
  int b = (int)roi[0];
  b = (b < 0) ? 0 : (b >= RB ? RB - 1 : b);
  const float sw    = roi[1] * kScale;
  const float sh    = roi[2] * kScale;
  const float ew    = roi[3] * kScale;
  const float eh    = roi[4] * kScale;
  const float roi_w = fmaxf(ew - sw, 1.0f);
  const float roi_h = fmaxf(eh - sh, 1.0f);
  const float bin_w = roi_w / 7.0f;
  const float bin_h = roi_h / 7.0f;

  const float* fb = feat + ((size_t)b * RC + c) * RHW;

  for (int bi = 0; bi < RNB; ++bi) {
    const int ph = bi / RPW;
    const int pw = bi - ph * RPW;
    float acc = 0.f;
#pragma unroll
    for (int s = 0; s < 4; ++s) {
      const int iy = s >> 1;
      const int ix = s & 1;
      const float y = sh + ((float)ph + (iy ? 0.75f : 0.25f)) * bin_h;
      const float x = sw + ((float)pw + (ix ? 0.75f : 0.25f)) * bin_w;
      if (y < -1.0f || y > (float)RH || x < -1.0f || x > (float)RW) continue;

      const float yc = fminf(fmaxf(y, 0.0f), (float)(RH - 1));
      const float xc = fminf(fmaxf(x, 0.0f), (float)(RW - 1));
      const int y0 = (int)yc;
      const int x0 = (int)xc;
      const int y1 = (y0 + 1 < RH) ? y0 + 1 : RH - 1;
      const int x1 = (x0 + 1 < RW) ? x0 + 1 : RW - 1;
      const float ly = yc - (float)y0;
      const float lx = xc - (float)x0;
      const float hy = 1.0f - ly;
      const float hx = 1.0f - lx;

      acc += (hy * hx) * fb[y0 * RW + x0] + (hy * lx) * fb[y0 * RW + x1] +
             (ly * hx) * fb[y1 * RW + x0] + (ly * lx) * fb[y1 * RW + x1];
    }
    out[((size_t)r * RC + c) * RNB + bi] = acc * 0.25f;
  }
}

// ---------------------------------------------------------------------------
extern "C" void kernel_launch(void* const* d_in, const int* in_sizes, int n_in,
                              void* d_out, int out_size, void* d_ws, size_t ws_size,
                              hipStream_t stream) {
  const float* feat = (const float*)d_in[0];
  const float* rois = (const float*)d_in[1];
  float* out = (float*)d_out;
  const int R = in_sizes[1] / 5;

  const size_t need = (size_t)RB * RC * RHW * sizeof(float);  // 31.1 MB
  const bool aligned16 =
      (((uintptr_t)d_ws | (uintptr_t)d_in[0] | (uintptr_t)d_out) & 15) == 0;

  if (ws_size >= need && aligned16 && d_ws != nullptr) {
    float* nhwc = (float*)d_ws;
    transpose_nchw_nhwc<<<RB * 8 * HTILES, 256, 0, stream>>>(feat, nhwc);
    roi_align_nhwc<<<R * 2, 256, 0, stream>>>(nhwc, rois, out);
  } else {
    roi_align_nchw<<<R, 256, 0, stream>>>(feat, rois, out);
  }
}

// Round 5
// 113.562 us; speedup vs baseline: 1.3144x; 1.2610x over previous
//
#include <hip/hip_runtime.h>
#include <cstdint>
#include <cstddef>

// Problem constants (from reference setup_inputs / module constants)
#define RB  2
#define RC  256
#define RH  100
#define RW  152
#define RHW (RH * RW)      // 15200
#define HWQ (RHW / 4)      // 3800 float4 per channel row
#define RPH 7
#define RPW 7
#define RNB (RPH * RPW)    // 49 bins per ROI
#define HTILES ((HWQ + 31) / 32)   // 119 hw-quad tiles (128 hw elems each)
constexpr float kScale = 0.0625f;

// float -> bf16 (RNE), result in low 16 bits
__device__ __forceinline__ uint32_t f2bf(float f) {
  const uint32_t u = __float_as_uint(f);
  return (u + 0x7fffu + ((u >> 16) & 1u)) >> 16;
}
// packed-bf16 dword -> two floats
#define BFLO(p) __uint_as_float((p) << 16)
#define BFHI(p) __uint_as_float((p) & 0xffff0000u)

// ---------------------------------------------------------------------------
// Kernel 1: NCHW fp32 -> NHWC bf16.  float4 global loads, uint2 (4xbf16)
// global stores, element transpose via LDS tile (32 c x 128 hw).
// Memory layout out: ushort[B][HW][C]; dword k of a position = ch 2k (lo),
// 2k+1 (hi).
// ---------------------------------------------------------------------------
__global__ __launch_bounds__(256) void transpose_nchw_nhwc_bf16(
    const float* __restrict__ in, uint32_t* __restrict__ out) {
  __shared__ float lds[128 * 33];   // [hw 0..127][c 0..31], +1 pad
  int bid = blockIdx.x;             // 0 .. RB*8*HTILES-1
  const int b  = bid / (8 * HTILES);
  bid -= b * (8 * HTILES);
  const int c0 = (bid / HTILES) * 32;
  const int ht = bid - (bid / HTILES) * HTILES;
  const int t  = threadIdx.x;

  const float4* in4  = (const float4*)(in + (size_t)b * RC * RHW);
  uint32_t*     outb = out + (size_t)b * RHW * 128;   // 128 dwords/position

  {  // phase 1: read [c][hw] float4, scatter scalars to lds[hw][c]
    const int tx = t & 31;          // hw-quad within tile
    const int ty = t >> 5;          // channel 0..7 (x4 iters)
    const int qt = ht * 32 + tx;    // global hw-quad
    if (qt < HWQ) {
#pragma unroll
      for (int j = 0; j < 4; ++j) {
        const int cl = ty + 8 * j;
        const float4 v = in4[(size_t)(c0 + cl) * HWQ + qt];
        const int hwl = tx * 4;
        lds[(hwl + 0) * 33 + cl] = v.x;
        lds[(hwl + 1) * 33 + cl] = v.y;
        lds[(hwl + 2) * 33 + cl] = v.z;
        lds[(hwl + 3) * 33 + cl] = v.w;
      }
    }
  }
  __syncthreads();
  {  // phase 2: gather 4 consecutive channels of one hw, pack bf16, store 8B
    const int cq = t & 7;           // channel quad: c = c0 + 4cq .. +3
    const int hr = t >> 3;          // hw row 0..31 (x4 iters)
#pragma unroll
    for (int j = 0; j < 4; ++j) {
      const int hwl = hr + 32 * j;
      const int hw  = ht * 128 + hwl;
      if (hw < RHW) {
        const float o0 = lds[hwl * 33 + 4 * cq + 0];
        const float o1 = lds[hwl * 33 + 4 * cq + 1];
        const float o2 = lds[hwl * 33 + 4 * cq + 2];
        const float o3 = lds[hwl * 33 + 4 * cq + 3];
        uint2 pk;
        pk.x = f2bf(o0) | (f2bf(o1) << 16);
        pk.y = f2bf(o2) | (f2bf(o3) << 16);
        ((uint2*)outb)[(size_t)hw * 64 + (c0 >> 2) + cq] = pk;
      }
    }
  }
}

// ---------------------------------------------------------------------------
// Kernel 2: RoIAlign gather on NHWC-bf16. Two blocks per ROI (128 ch each).
// Phase A (once): 196 threads precompute per-(bin,sample) fused weights
//   (validity folded in) and pre-scaled dword offsets into a 6.3 KB LDS table.
// Phase B: wave wg handles bins wg, wg+4, ... ; lane cg loads 1 packed dword
//   (2 bf16 channels) per corner, 16 loads issued back-to-back, weights via
//   broadcast ds_read_b128. No per-bin coordinate math at all.
// Stage results as packed bf16 in LDS [ch_pair][bin] -> coalesced epilogue.
// LDS total 18816 B -> 8 blocks/CU; grid 2048 = exactly 8/CU; 32 waves/CU.
// ---------------------------------------------------------------------------
__global__ __launch_bounds__(256, 8) void roi_align_gather(
    const uint32_t* __restrict__ feat,   // bf16x2 [B][HW][128]
    const float* __restrict__ rois,      // [R][5]
    float* __restrict__ out) {           // [R][C][7][7] fp32
  __shared__ float4   twgt[RNB * 4];     // [bi*4+s] = w11,w12,w21,w22 (masked)
  __shared__ int4     toff[RNB * 4];     // [bi*4+s] = dword offs (pos*128)
  __shared__ uint32_t stage[64 * RNB];   // [ch_pair][bi] packed bf16

  const int r    = blockIdx.x >> 1;
  const int half = blockIdx.x & 1;
  const int t    = threadIdx.x;
  const int cg   = t & 63;   // channel pair: ch = half*128 + 2cg, +1
  const int wg   = t >> 6;   // wave id 0..3

  const float* roi = rois + (size_t)r * 5;
  int b = (int)roi[0];
  b = (b < 0) ? 0 : (b >= RB ? RB - 1 : b);
  const float sw    = roi[1] * kScale;
  const float sh    = roi[2] * kScale;
  const float ew    = roi[3] * kScale;
  const float eh    = roi[4] * kScale;
  const float bin_w = fmaxf(ew - sw, 1.0f) * (1.0f / 7.0f);
  const float bin_h = fmaxf(eh - sh, 1.0f) * (1.0f / 7.0f);

  // ---- Phase A: build the (bin,sample) table --------------------------------
  if (t < RNB * 4) {
    const int bi = t >> 2;
    const int s  = t & 3;
    const int ph = bi / RPW;
    const int pw = bi - ph * RPW;
    const int iy = s >> 1;
    const int ix = s & 1;
    const float y  = sh + ((float)ph + (iy ? 0.75f : 0.25f)) * bin_h;
    const float x  = sw + ((float)pw + (ix ? 0.75f : 0.25f)) * bin_w;
    const float vm = ((y >= -1.0f && y <= (float)RH) &&
                      (x >= -1.0f && x <= (float)RW)) ? 1.0f : 0.0f;
    const float yc = fminf(fmaxf(y, 0.0f), (float)(RH - 1));
    const float xc = fminf(fmaxf(x, 0.0f), (float)(RW - 1));
    const int y0 = (int)yc;
    const int x0 = (int)xc;
    const int y1 = (y0 + 1 < RH) ? y0 + 1 : RH - 1;
    const int x1 = (x0 + 1 < RW) ? x0 + 1 : RW - 1;
    const float ly = yc - (float)y0;
    const float lx = xc - (float)x0;
    const float hy = 1.0f - ly;
    const float hx = 1.0f - lx;
    twgt[t] = make_float4(hy * hx * vm, hy * lx * vm, ly * hx * vm, ly * lx * vm);
    toff[t] = make_int4((y0 * RW + x0) * 128, (y0 * RW + x1) * 128,
                        (y1 * RW + x0) * 128, (y1 * RW + x1) * 128);
  }
  __syncthreads();

  // ---- Phase B: gather ------------------------------------------------------
  const uint32_t* fb = feat + (size_t)b * RHW * 128;
  const int ln = half * 64 + cg;   // dword offset within a position

#pragma unroll 1
  for (int bi = wg; bi < RNB; bi += 4) {
    const int4 o0 = toff[bi * 4 + 0];
    const int4 o1 = toff[bi * 4 + 1];
    const int4 o2 = toff[bi * 4 + 2];
    const int4 o3 = toff[bi * 4 + 3];
    // 16 loads, all independent, issued back-to-back
    const uint32_t p00 = fb[o0.x + ln], p01 = fb[o0.y + ln],
                   p02 = fb[o0.z + ln], p03 = fb[o0.w + ln];
    const uint32_t p10 = fb[o1.x + ln], p11 = fb[o1.y + ln],
                   p12 = fb[o1.z + ln], p13 = fb[o1.w + ln];
    const uint32_t p20 = fb[o2.x + ln], p21 = fb[o2.y + ln],
                   p22 = fb[o2.z + ln], p23 = fb[o2.w + ln];
    const uint32_t p30 = fb[o3.x + ln], p31 = fb[o3.y + ln],
                   p32 = fb[o3.z + ln], p33 = fb[o3.w + ln];
    const float4 w0 = twgt[bi * 4 + 0];
    const float4 w1 = twgt[bi * 4 + 1];
    const float4 w2 = twgt[bi * 4 + 2];
    const float4 w3 = twgt[bi * 4 + 3];

    float ax, ay;
    ax  = w0.x * BFLO(p00) + w0.y * BFLO(p01) + w0.z * BFLO(p02) + w0.w * BFLO(p03);
    ay  = w0.x * BFHI(p00) + w0.y * BFHI(p01) + w0.z * BFHI(p02) + w0.w * BFHI(p03);
    ax += w1.x * BFLO(p10) + w1.y * BFLO(p11) + w1.z * BFLO(p12) + w1.w * BFLO(p13);
    ay += w1.x * BFHI(p10) + w1.y * BFHI(p11) + w1.z * BFHI(p12) + w1.w * BFHI(p13);
    ax += w2.x * BFLO(p20) + w2.y * BFLO(p21) + w2.z * BFLO(p22) + w2.w * BFLO(p23);
    ay += w2.x * BFHI(p20) + w2.y * BFHI(p21) + w2.z * BFHI(p22) + w2.w * BFHI(p23);
    ax += w3.x * BFLO(p30) + w3.y * BFLO(p31) + w3.z * BFLO(p32) + w3.w * BFLO(p33);
    ay += w3.x * BFHI(p30) + w3.y * BFHI(p31) + w3.z * BFHI(p32) + w3.w * BFHI(p33);

    // stage packed bf16: row = channel pair cg, col = bin (2-way bank, free)
    stage[cg * RNB + bi] = f2bf(ax * 0.25f) | (f2bf(ay * 0.25f) << 16);
  }
  __syncthreads();

  // ---- Epilogue: 6272 fp32, fully coalesced ---------------------------------
  float* outr = out + (size_t)r * (RC * RNB) + half * (128 * RNB);
#pragma unroll
  for (int it = 0; it < 24; ++it) {
    const int o  = it * 256 + t;
    const int cl = o / RNB;            // local channel 0..127
    const int bi = o - cl * RNB;
    const uint32_t d = stage[(cl >> 1) * RNB + bi];
    outr[o] = (cl & 1) ? BFHI(d) : BFLO(d);
  }
  if (t < 128) {
    const int o  = 24 * 256 + t;
    const int cl = o / RNB;
    const int bi = o - cl * RNB;
    const uint32_t d = stage[(cl >> 1) * RNB + bi];
    outr[o] = (cl & 1) ? BFHI(d) : BFLO(d);
  }
}

// ---------------------------------------------------------------------------
// Fallback: direct NCHW fp32 gather (workspace too small / misaligned).
// ---------------------------------------------------------------------------
__global__ __launch_bounds__(256) void roi_align_nchw(
    const float* __restrict__ feat,   // [B][C][H][W]
    const float* __restrict__ rois,
    float* __restrict__ out) {
  const int r = blockIdx.x;
  const int c = threadIdx.x;

  const float* roi = rois + (size_t)r * 5;
  int b = (int)roi[0];
  b = (b < 0) ? 0 : (b >= RB ? RB - 1 : b);
  const float sw    = roi[1] * kScale;
  const float sh    = roi[2] * kScale;
  const float ew    = roi[3] * kScale;
  const float eh    = roi[4] * kScale;
  const float bin_w = fmaxf(ew - sw, 1.0f) / 7.0f;
  const float bin_h = fmaxf(eh - sh, 1.0f) / 7.0f;

  const float* fb = feat + ((size_t)b * RC + c) * RHW;

  for (int bi = 0; bi < RNB; ++bi) {
    const int ph = bi / RPW;
    const int pw = bi - ph * RPW;
    float acc = 0.f;
#pragma unroll
    for (int s = 0; s < 4; ++s) {
      const int iy = s >> 1;
      const int ix = s & 1;
      const float y = sh + ((float)ph + (iy ? 0.75f : 0.25f)) * bin_h;
      const float x = sw + ((float)pw + (ix ? 0.75f : 0.25f)) * bin_w;
      if (y < -1.0f || y > (float)RH || x < -1.0f || x > (float)RW) continue;

      const float yc = fminf(fmaxf(y, 0.0f), (float)(RH - 1));
      const float xc = fminf(fmaxf(x, 0.0f), (float)(RW - 1));
      const int y0 = (int)yc;
      const int x0 = (int)xc;
      const int y1 = (y0 + 1 < RH) ? y0 + 1 : RH - 1;
      const int x1 = (x0 + 1 < RW) ? x0 + 1 : RW - 1;
      const float ly = yc - (float)y0;
      const float lx = xc - (float)x0;
      const float hy = 1.0f - ly;
      const float hx = 1.0f - lx;

      acc += (hy * hx) * fb[y0 * RW + x0] + (hy * lx) * fb[y0 * RW + x1] +
             (ly * hx) * fb[y1 * RW + x0] + (ly * lx) * fb[y1 * RW + x1];
    }
    out[((size_t)r * RC + c) * RNB + bi] = acc * 0.25f;
  }
}

// ---------------------------------------------------------------------------
extern "C" void kernel_launch(void* const* d_in, const int* in_sizes, int n_in,
                              void* d_out, int out_size, void* d_ws, size_t ws_size,
                              hipStream_t stream) {
  const float* feat = (const float*)d_in[0];
  const float* rois = (const float*)d_in[1];
  float* out = (float*)d_out;
  const int R = in_sizes[1] / 5;

  const size_t need = (size_t)RB * RHW * RC * sizeof(uint16_t);  // 15.6 MB
  const bool aligned16 =
      (((uintptr_t)d_ws | (uintptr_t)d_in[0] | (uintptr_t)d_out) & 15) == 0;

  if (ws_size >= need && aligned16 && d_ws != nullptr) {
    uint32_t* nhwc = (uint32_t*)d_ws;
    transpose_nchw_nhwc_bf16<<<RB * 8 * HTILES, 256, 0, stream>>>(feat, nhwc);
    roi_align_gather<<<R * 2, 256, 0, stream>>>(nhwc, rois, out);
  } else {
    roi_align_nchw<<<R, 256, 0, stream>>>(feat, rois, out);
  }
}